// Round 2
// 62.539 us; speedup vs baseline: 1.0039x; 1.0039x over previous
//
#include <hip/hip_runtime.h>

#define NL 50
#define V_DIM 4096
#define THREADS 1024

__global__ __launch_bounds__(1024) void ZWeightedSum_kernel(
    const float* __restrict__ x,      // (B, V, 2)
    const float* __restrict__ weight, // (NL, 1)
    const float* __restrict__ bias,   // (NL,)
    float* __restrict__ out)          // (B,)
{
    // packed (lo, hi, w, 0) table; 50 real entries + sentinels, one ds_read_b128 per probe
    __shared__ float4 s_tab[64];
    __shared__ float  s_part[16];

    const int t = threadIdx.x;
    const int b = blockIdx.x;
    const float4* xb = (const float4*)(x + (size_t)b * (size_t)(V_DIM * 2));

    // ---- issue ALL global loads up front; HBM latency overlaps table setup ----
    float4 p0 = xb[t];             // (z0,v0,z1,v1)
    float4 p1 = xb[t + THREADS];

    // bias·weight term: straight from global, no LDS/barrier dependency.
    // Same accumulation order/values as baseline's bias[l]*s_tab[l].z loop.
    float bw = 0.0f;
    if (t == 0) {
        #pragma unroll
        for (int l = 0; l < NL; ++l) bw += bias[l] * weight[l];
    }

    if (t < 64) {
        float lo, hi, w;
        if (t < NL) {
            // exact numpy edge construction: f64 arange, /200.0, *(120/200), cast f32
            double l = (double)t;
            double lowd, highd;
            if (t < 25) { lowd = l;                    highd = l + 1.0; }
            else        { lowd = 25.0 + 7.0*(l-25.0);  highd = 32.0 + 7.0*(l-25.0); }
            const double f = 120.0 / 200.0;
            lo = (float)((lowd  / 200.0) * f);
            hi = (float)((highd / 200.0) * f);
            w  = weight[t];
        } else {
            lo = 1e30f; hi = -1e30f; w = 0.0f;  // sentinel: never matches
        }
        s_tab[t] = make_float4(lo, hi, w, 0.0f);
    }
    __syncthreads();

    const float C1 = 1000.0f / 3.0f;   // 1 / bin_width for the unit-stride region

    float acc = 0.0f;
    // same element order as baseline: (p0.x,p0.y),(p0.z,p0.w),(p1.x,p1.y),(p1.z,p1.w)
    float zz[4] = { p0.x, p0.z, p1.x, p1.z };
    float vv[4] = { p0.y, p0.w, p1.y, p1.w };
    #pragma unroll
    for (int e = 0; e < 4; ++e) {
        const float z = zz[e];
        const float u = z * C1;
        // candidate bin (truncation == floor since u >= 0)
        int ca = (int)u;
        int cb = 25 + (int)((u - 25.0f) * (1.0f / 7.0f));
        int c  = (u < 25.5f) ? ca : cb;
        c = min(max(c, 0), 49);        // c in [0,49] -> probes hit [0,50] only
        // verify c-1, c, c+1 against exact f32 edges (absorbs fp rounding)
        float weff = 0.0f;
        const int l0 = max(c - 1, 0);
        #pragma unroll
        for (int j = 0; j <= 2; ++j) {
            int l = (j == 0) ? l0 : (c - 1 + j);
            float4 e4 = s_tab[l];      // one ds_read_b128
            if (z > e4.x && z < e4.y) weff = e4.z;
        }
        acc += vv[e] * weff;
    }

    // wave-64 butterfly reduce (identical to baseline)
    #pragma unroll
    for (int off = 32; off > 0; off >>= 1)
        acc += __shfl_down(acc, off, 64);

    if ((t & 63) == 0) s_part[t >> 6] = acc;
    __syncthreads();

    if (t == 0) {
        float s = bw;
        #pragma unroll
        for (int i = 0; i < 16; ++i) s += s_part[i];
        out[b] = s;
    }
}

extern "C" void kernel_launch(void* const* d_in, const int* in_sizes, int n_in,
                              void* d_out, int out_size, void* d_ws, size_t ws_size,
                              hipStream_t stream) {
    const float* x      = (const float*)d_in[0];
    const float* weight = (const float*)d_in[1];
    const float* bias   = (const float*)d_in[2];
    float* out          = (float*)d_out;

    const int B = in_sizes[0] / (V_DIM * 2);  // 256
    ZWeightedSum_kernel<<<B, THREADS, 0, stream>>>(x, weight, bias, out);
}